// Round 4
// baseline (351.945 us; speedup 1.0000x reference)
//
#include <hip/hip_runtime.h>
#include <math.h>

// Problem constants (fixed by setup_inputs)
#define NB 2
#define NH 12
#define NW 12
#define NK 3
#define NI 32
#define NO 32
#define NBHW (NB*NH*NW)        // 288 spatial positions
#define NC (NK*NK*NI)          // 288 children per position
#define VPB (NC*NO*16)         // 147456 votes floats per bhw (o-major, a-minor)
#define HR 14
#define WR 14
#define EPSF 1e-7f
#define MINVAR 5e-4f
#define TEMP0 0.0005f          // 0.01*(1-0.95^1), m_step it=0
#define TEMPF 0.00142625f      // 0.01*(1-0.95^3), final m_step

// CH=8: grid 2304. Round-3 A/B proved occupancy (18 vs 32 waves/CU) is NOT
// the limiter; this round probes per-wave load pipelining instead:
// launch_bounds(256,6) -> ~85 VGPR budget (vs 64) + full unroll of the
// 9-iter votes loop so the compiler can keep 8+ loads in flight per wave.
#define CH 8
#define CPC (NC/CH)            // 36 children per unit
#define UNITS (NBHW*CH)        // 2304 work units
#define ITERS (CPC/4)          // 9 iters, 4 children per block-iter

// ---- Workspace layout (float offsets) ----
// S1/S2 are now single merged slots per unit (halves combined in LDS).
#define DENSE_N (NB*HR*WR*NI)  // 12544
#define DENSE_OFF 0
#define S1_OFF    (DENSE_OFF + DENSE_N)      // [UNITS][512]
#define S2_OFF    (S1_OFF + UNITS*512)
#define SR_OFF    (S2_OFF + UNITS*512)       // [UNITS]
#define MU_OFF    (SR_OFF + UNITS)           // [288][512] stored (a*32+o)
#define W_OFF     (MU_OFF + NBHW*512)        // 0.5/sig, same layout
#define L_OFF     (W_OFF + NBHW*512)         // [288][32]
#define BM_OFF    (L_OFF + NBHW*32)          // [UNITS] per-unit lognum max
#define LOG_OFF   (BM_OFF + UNITS)           // [288][288][32] lognum
#define DSR_OFF   (LOG_OFF + NBHW*NC*NO)     // [UNITS][32] per-o sumR

// ================= kA: m_step 1 partial moments (R uniform = 1/NO) =========
// grid = UNITS, block = 256. Also zeroes the dense grid.
__global__ __launch_bounds__(256, 6) void kA(const float* __restrict__ votes,
        const float* __restrict__ acts, float* __restrict__ ws) {
    __shared__ float s_acts[CPC];
    __shared__ float4 r1[128], r2[128];
    __shared__ float sR1;
    const int u = blockIdx.x;
    const int t = threadIdx.x;
    {   // fold dense-grid zeroing into the first kernel
        const int idx = u*256 + t;
        if (idx < DENSE_N) ws[DENSE_OFF + idx] = 0.f;
    }
    const int bhw = u >> 3;
    const int cbase = (u & 7)*CPC;
    if (t < CPC) s_acts[t] = acts[bhw*NC + cbase + t] * (1.0f/NO);
    __syncthreads();
    const int child_sub = t >> 7;
    const int rem = t & 127;
    const float4* vb4 = (const float4*)votes + (size_t)bhw*(VPB/4) + (size_t)cbase*128;
    float s1[4] = {0,0,0,0}, s2[4] = {0,0,0,0};
    float sumR = 0.f;
    #pragma unroll
    for (int it = 0; it < ITERS; ++it) {
        const int c0 = it*4 + child_sub, c1 = c0 + 2;
        float4 v0 = vb4[(size_t)c0*128 + rem];
        float4 v1 = vb4[(size_t)c1*128 + rem];
        float ra0 = s_acts[c0], ra1 = s_acts[c1];
        float w;
        w = ra0*v0.x; s1[0] += w; s2[0] = fmaf(w, v0.x, s2[0]);
        w = ra0*v0.y; s1[1] += w; s2[1] = fmaf(w, v0.y, s2[1]);
        w = ra0*v0.z; s1[2] += w; s2[2] = fmaf(w, v0.z, s2[2]);
        w = ra0*v0.w; s1[3] += w; s2[3] = fmaf(w, v0.w, s2[3]);
        w = ra1*v1.x; s1[0] += w; s2[0] = fmaf(w, v1.x, s2[0]);
        w = ra1*v1.y; s1[1] += w; s2[1] = fmaf(w, v1.y, s2[1]);
        w = ra1*v1.z; s1[2] += w; s2[2] = fmaf(w, v1.z, s2[2]);
        w = ra1*v1.w; s1[3] += w; s2[3] = fmaf(w, v1.w, s2[3]);
        sumR += ra0 + ra1;
    }
    // merge halves in LDS: one 512-float slot per unit (halves S1/S2 traffic)
    if (child_sub) {
        r1[rem] = make_float4(s1[0], s1[1], s1[2], s1[3]);
        r2[rem] = make_float4(s2[0], s2[1], s2[2], s2[3]);
        if (rem == 0) sR1 = sumR;
    }
    __syncthreads();
    if (!child_sub) {
        float4 o1 = r1[rem], o2 = r2[rem];
        ((float4*)(ws + S1_OFF))[u*128 + rem] =
            make_float4(s1[0]+o1.x, s1[1]+o1.y, s1[2]+o1.z, s1[3]+o1.w);
        ((float4*)(ws + S2_OFF))[u*128 + rem] =
            make_float4(s2[0]+o2.x, s2[1]+o2.y, s2[2]+o2.z, s2[3]+o2.w);
        if (rem == 0) ws[SR_OFF + u] = sumR + sR1;
    }
}

// ================= kB0: per-bhw finalize (once per bhw) =====================
// grid = NBHW, block = 128; thread t owns float4 idx = 4t..4t+3 (o = t>>2).
__global__ __launch_bounds__(128) void kB0(const float* __restrict__ beta_a,
        const float* __restrict__ beta_u, float* __restrict__ ws) {
    const int bhw = blockIdx.x;
    const int t = threadIdx.x;
    float sumR = 0.f;
    #pragma unroll
    for (int s = 0; s < 8; ++s) sumR += ws[SR_OFF + bhw*8 + s];
    float4 s1v = make_float4(0,0,0,0), s2v = make_float4(0,0,0,0);
    #pragma unroll
    for (int s = 0; s < 8; ++s) {
        float4 a4 = ((const float4*)(ws + S1_OFF))[(size_t)(bhw*8 + s)*128 + t];
        float4 b4 = ((const float4*)(ws + S2_OFF))[(size_t)(bhw*8 + s)*128 + t];
        s1v.x += a4.x; s1v.y += a4.y; s1v.z += a4.z; s1v.w += a4.w;
        s2v.x += b4.x; s2v.y += b4.y; s2v.z += b4.z; s2v.w += b4.w;
    }
    const int o = t >> 2;
    const float bu = beta_u[o];
    const float s1a[4] = {s1v.x, s1v.y, s1v.z, s1v.w};
    const float s2a[4] = {s2v.x, s2v.y, s2v.z, s2v.w};
    float cost = 0.f, ps = 0.f;
    #pragma unroll
    for (int j = 0; j < 4; ++j) {
        const int a = (4*t + j) & 15;
        float mu  = s1a[j] / (sumR + EPSF);
        float sig = (s2a[j] - mu*(2.f*s1a[j] - mu*sumR)) / (sumR + EPSF) + MINVAR;
        ws[MU_OFF + bhw*512 + a*32 + o] = mu;
        ws[W_OFF  + bhw*512 + a*32 + o] = 0.5f / sig;
        cost += (bu - 0.5f*logf(sig + EPSF)) * sumR;
        ps   += logf(6.2831853071795864f * sig);
    }
    cost += __shfl_xor(cost, 1); cost += __shfl_xor(cost, 2);
    ps   += __shfl_xor(ps, 1);   ps   += __shfl_xor(ps, 2);
    if ((t & 3) == 0) {
        float aj = 1.0f/(1.0f + expf(-TEMP0*(beta_a[o] - cost)));
        ws[L_OFF + bhw*32 + o] = logf(aj) - ps;
    }
}

// ================= kB: lognum pass over votes ===============================
// grid = UNITS, block = 256.
__global__ __launch_bounds__(256, 6) void kB(const float* __restrict__ votes,
        float* __restrict__ ws) {
    __shared__ float s_mu[512], s_w[512], s_L[32], smax[4];
    const int u = blockIdx.x;
    const int bhw = u >> 3;
    const int cbase = (u & 7)*CPC;
    const int t = threadIdx.x;
    const int child_sub = t >> 7;
    const int rem = t & 127;
    s_mu[t]     = ws[MU_OFF + bhw*512 + t];
    s_mu[t+256] = ws[MU_OFF + bhw*512 + t + 256];
    s_w[t]      = ws[W_OFF + bhw*512 + t];
    s_w[t+256]  = ws[W_OFF + bhw*512 + t + 256];
    if (t < 32) s_L[t] = ws[L_OFF + bhw*32 + t];
    __syncthreads();
    const int o = rem >> 2, quad = rem & 3;
    float mur[4], wr[4];
    #pragma unroll
    for (int j = 0; j < 4; ++j) {
        mur[j] = s_mu[(quad*4 + j)*32 + o];
        wr[j]  = s_w [(quad*4 + j)*32 + o];
    }
    const float L = s_L[o];
    const float4* vb4 = (const float4*)votes + (size_t)bhw*(VPB/4) + (size_t)cbase*128;
    float* lp = ws + LOG_OFF + (size_t)(bhw*NC + cbase)*32;
    float tmax = -3.0e38f;
    #pragma unroll
    for (int it = 0; it < ITERS; ++it) {
        const int c0 = it*4 + child_sub, c1 = c0 + 2;
        float4 v0 = vb4[(size_t)c0*128 + rem];
        float4 v1 = vb4[(size_t)c1*128 + rem];
        float d, acc0, acc1;
        d = v0.x - mur[0]; acc0 = d*d*wr[0];
        d = v0.y - mur[1]; acc0 = fmaf(d*d, wr[1], acc0);
        d = v0.z - mur[2]; acc0 = fmaf(d*d, wr[2], acc0);
        d = v0.w - mur[3]; acc0 = fmaf(d*d, wr[3], acc0);
        d = v1.x - mur[0]; acc1 = d*d*wr[0];
        d = v1.y - mur[1]; acc1 = fmaf(d*d, wr[1], acc1);
        d = v1.z - mur[2]; acc1 = fmaf(d*d, wr[2], acc1);
        d = v1.w - mur[3]; acc1 = fmaf(d*d, wr[3], acc1);
        acc0 += __shfl_xor(acc0, 1); acc0 += __shfl_xor(acc0, 2);
        acc1 += __shfl_xor(acc1, 1); acc1 += __shfl_xor(acc1, 2);
        float ln0 = L - acc0, ln1 = L - acc1;
        if (quad == 0) { lp[c0*32 + o] = ln0; lp[c1*32 + o] = ln1; }
        tmax = fmaxf(tmax, fmaxf(ln0, ln1));
    }
    #pragma unroll
    for (int d = 1; d < 64; d <<= 1) tmax = fmaxf(tmax, __shfl_xor(tmax, d));
    if ((t & 63) == 0) smax[t >> 6] = tmax;
    __syncthreads();
    if (t == 0)
        ws[BM_OFF + u] = fmaxf(fmaxf(smax[0], smax[1]), fmaxf(smax[2], smax[3]));
}

// ================= kC: global max + exp/sum_o + scatter to dense ============
// grid = UNITS, block = 256.
__global__ __launch_bounds__(256, 8) void kC(float* __restrict__ ws) {
    __shared__ float smax[4];
    const int u = blockIdx.x;
    const int bhw = u >> 3;
    const int cbase = (u & 7)*CPC;
    const int t = threadIdx.x;
    float m = -3.0e38f;
    for (int i = t; i < UNITS; i += 256) m = fmaxf(m, ws[BM_OFF + i]);
    #pragma unroll
    for (int d = 1; d < 64; d <<= 1) m = fmaxf(m, __shfl_xor(m, d));
    if ((t & 63) == 0) smax[t >> 6] = m;
    __syncthreads();
    const float M = fmaxf(fmaxf(smax[0], smax[1]), fmaxf(smax[2], smax[3]));
    const int b = bhw / (NH*NW);
    const int remhw = bhw % (NH*NW);
    const int y = remhw / NW, x = remhw % NW;
    const float* lp = ws + LOG_OFF + (size_t)(bhw*NC + cbase)*32;
    const int o = t & 31, cg = t >> 5;
    for (int it = 0; it < 5; ++it) {
        const int c_loc = it*8 + cg;
        const bool act = c_loc < CPC;
        float s = act ? expf(lp[c_loc*32 + o] - M) : 0.f;
        #pragma unroll
        for (int d = 1; d < 32; d <<= 1) s += __shfl_xor(s, d);
        if (act && o == 0) {
            const int c = cbase + c_loc;
            const int i = c & 31, kk = c >> 5;
            const int ky = kk / 3, kx = kk % 3;
            atomicAdd(ws + DENSE_OFF + ((b*HR + y+ky)*WR + (x+kx))*NI + i, s);
        }
    }
}

// ================= kD: final m_step partial moments =========================
// grid = UNITS, block = 256.
__global__ __launch_bounds__(256, 6) void kD(const float* __restrict__ votes,
        const float* __restrict__ acts, float* __restrict__ ws) {
    __shared__ float s_rd[CPC];
    __shared__ float s_ra[CPC*NO];
    __shared__ float smax[4];
    __shared__ float sSR[64];
    __shared__ float4 r1[128], r2[128];
    const int u = blockIdx.x;
    const int bhw = u >> 3;
    const int cbase = (u & 7)*CPC;
    const int t = threadIdx.x;
    const int b = bhw / (NH*NW);
    const int remhw = bhw % (NH*NW);
    const int y = remhw / NW, x = remhw % NW;
    float m = -3.0e38f;
    for (int i = t; i < UNITS; i += 256) m = fmaxf(m, ws[BM_OFF + i]);
    #pragma unroll
    for (int d = 1; d < 64; d <<= 1) m = fmaxf(m, __shfl_xor(m, d));
    if ((t & 63) == 0) smax[t >> 6] = m;
    if (t < CPC) {
        const int c = cbase + t;
        const int i = c & 31, kk = c >> 5;
        const int ky = kk / 3, kx = kk % 3;
        float dn = ws[DENSE_OFF + ((b*HR + y+ky)*WR + (x+kx))*NI + i];
        s_rd[t] = acts[bhw*NC + c] / (dn + EPSF);
    }
    __syncthreads();
    const float M = fmaxf(fmaxf(smax[0], smax[1]), fmaxf(smax[2], smax[3]));
    const float* lp = ws + LOG_OFF + (size_t)(bhw*NC + cbase)*32;
    for (int idx = t; idx < CPC*NO; idx += 256)
        s_ra[idx] = s_rd[idx >> 5] * expf(lp[idx] - M);
    __syncthreads();
    const int child_sub = t >> 7;
    const int rem = t & 127;
    const int o = rem >> 2, quad = rem & 3;
    const float4* vb4 = (const float4*)votes + (size_t)bhw*(VPB/4) + (size_t)cbase*128;
    float s1[4] = {0,0,0,0}, s2[4] = {0,0,0,0};
    float sumR = 0.f;
    #pragma unroll
    for (int it = 0; it < ITERS; ++it) {
        const int c0 = it*4 + child_sub, c1 = c0 + 2;
        float4 v0 = vb4[(size_t)c0*128 + rem];
        float4 v1 = vb4[(size_t)c1*128 + rem];
        float ra0 = s_ra[c0*32 + o], ra1 = s_ra[c1*32 + o];
        float w;
        w = ra0*v0.x; s1[0] += w; s2[0] = fmaf(w, v0.x, s2[0]);
        w = ra0*v0.y; s1[1] += w; s2[1] = fmaf(w, v0.y, s2[1]);
        w = ra0*v0.z; s1[2] += w; s2[2] = fmaf(w, v0.z, s2[2]);
        w = ra0*v0.w; s1[3] += w; s2[3] = fmaf(w, v0.w, s2[3]);
        w = ra1*v1.x; s1[0] += w; s2[0] = fmaf(w, v1.x, s2[0]);
        w = ra1*v1.y; s1[1] += w; s2[1] = fmaf(w, v1.y, s2[1]);
        w = ra1*v1.z; s1[2] += w; s2[2] = fmaf(w, v1.z, s2[2]);
        w = ra1*v1.w; s1[3] += w; s2[3] = fmaf(w, v1.w, s2[3]);
        sumR += ra0 + ra1;
    }
    if (quad == 0) sSR[child_sub*32 + o] = sumR;   // quads identical
    if (child_sub) {
        r1[rem] = make_float4(s1[0], s1[1], s1[2], s1[3]);
        r2[rem] = make_float4(s2[0], s2[1], s2[2], s2[3]);
    }
    __syncthreads();
    if (!child_sub) {
        float4 o1 = r1[rem], o2 = r2[rem];
        ((float4*)(ws + S1_OFF))[u*128 + rem] =
            make_float4(s1[0]+o1.x, s1[1]+o1.y, s1[2]+o1.z, s1[3]+o1.w);
        ((float4*)(ws + S2_OFF))[u*128 + rem] =
            make_float4(s2[0]+o2.x, s2[1]+o2.y, s2[2]+o2.z, s2[3]+o2.w);
    }
    if (t < 32) ws[DSR_OFF + u*32 + t] = sSR[t] + sSR[32 + t];
}

// ================= kD2: reduce unit slots, write outputs ====================
// grid = NBHW, block = 128; thread t owns float4 idx = 4t..4t+3 (o = t>>2).
__global__ __launch_bounds__(128) void kD2(const float* __restrict__ beta_a,
        const float* __restrict__ beta_u, const float* __restrict__ ws,
        float* __restrict__ out) {
    const int bhw = blockIdx.x;
    const int t = threadIdx.x;
    const int o = t >> 2;
    float sumR = 0.f;
    #pragma unroll
    for (int ch = 0; ch < 8; ++ch) sumR += ws[DSR_OFF + (bhw*8 + ch)*32 + o];
    float4 s1v = make_float4(0,0,0,0), s2v = make_float4(0,0,0,0);
    #pragma unroll
    for (int ch = 0; ch < 8; ++ch) {
        float4 a4 = ((const float4*)(ws + S1_OFF))[(size_t)(bhw*8 + ch)*128 + t];
        float4 b4 = ((const float4*)(ws + S2_OFF))[(size_t)(bhw*8 + ch)*128 + t];
        s1v.x += a4.x; s1v.y += a4.y; s1v.z += a4.z; s1v.w += a4.w;
        s2v.x += b4.x; s2v.y += b4.y; s2v.z += b4.z; s2v.w += b4.w;
    }
    const float bu = beta_u[o];
    const float s1a[4] = {s1v.x, s1v.y, s1v.z, s1v.w};
    const float s2a[4] = {s2v.x, s2v.y, s2v.z, s2v.w};
    float mu4[4];
    float cost = 0.f;
    #pragma unroll
    for (int j = 0; j < 4; ++j) {
        float mu  = s1a[j] / (sumR + EPSF);
        float sig = (s2a[j] - mu*(2.f*s1a[j] - mu*sumR)) / (sumR + EPSF) + MINVAR;
        mu4[j] = mu;
        cost += (bu - 0.5f*logf(sig + EPSF)) * sumR;
    }
    ((float4*)out)[bhw*128 + t] =
        make_float4(mu4[0], mu4[1], mu4[2], mu4[3]);   // poses (b,h,w,o,a,a)
    cost += __shfl_xor(cost, 1); cost += __shfl_xor(cost, 2);
    if ((t & 3) == 0) {
        float aj = 1.0f/(1.0f + expf(-TEMPF*(beta_a[o] - cost)));
        out[NBHW*512 + bhw*32 + o] = aj;               // acts (b,h,w,o)
    }
}

extern "C" void kernel_launch(void* const* d_in, const int* in_sizes, int n_in,
                              void* d_out, int out_size, void* d_ws, size_t ws_size,
                              hipStream_t stream) {
    const float* votes  = (const float*)d_in[0];
    const float* acts   = (const float*)d_in[1];
    const float* beta_a = (const float*)d_in[2];
    const float* beta_u = (const float*)d_in[3];
    float* ws  = (float*)d_ws;
    float* out = (float*)d_out;

    kA <<<UNITS, 256, 0, stream>>>(votes, acts, ws);
    kB0<<<NBHW,  128, 0, stream>>>(beta_a, beta_u, ws);
    kB <<<UNITS, 256, 0, stream>>>(votes, ws);
    kC <<<UNITS, 256, 0, stream>>>(ws);
    kD <<<UNITS, 256, 0, stream>>>(votes, acts, ws);
    kD2<<<NBHW,  128, 0, stream>>>(beta_a, beta_u, ws, out);
}

// Round 5
// 311.117 us; speedup vs baseline: 1.1312x; 1.1312x over previous
//
#include <hip/hip_runtime.h>
#include <math.h>

// Problem constants (fixed by setup_inputs)
#define NB 2
#define NH 12
#define NW 12
#define NK 3
#define NI 32
#define NO 32
#define NBHW (NB*NH*NW)        // 288 spatial positions
#define NC (NK*NK*NI)          // 288 children per position
#define VPB (NC*NO*16)         // 147456 votes floats per bhw (o-major, a-minor)
#define HR 14
#define WR 14
#define EPSF 1e-7f
#define MINVAR 5e-4f
#define TEMP0 0.0005f          // 0.01*(1-0.95^1), m_step it=0
#define TEMPF 0.00142625f      // 0.01*(1-0.95^3), final m_step

// CH=4 proven best (R3: CH=8 + 32 waves/CU was NOT faster; R4: deeper
// unroll was NOT faster -> votes-pass rate is invariant to occupancy/ILP).
#define CH 4
#define CPC (NC/CH)            // 72 children per chunk
#define NBLK (NBHW*CH)         // 1152 chunk-blocks
#define ITERS (CPC/2)          // 36 iters, 2 children per block-iteration

// ---- Workspace layout (float offsets) ----
#define DENSE_N (NB*HR*WR*NI)  // 12544
#define DENSE_OFF 0
#define S1_OFF    (DENSE_OFF + DENSE_N)      // [NBLK][512] chunk partials
#define S2_OFF    (S1_OFF + NBLK*512)
#define SR_OFF    (S2_OFF + NBLK*512)        // [NBLK]
#define MU_OFF    (SR_OFF + NBLK)            // [288][512] stored (a*32+o)
#define W_OFF     (MU_OFF + NBHW*512)        // 0.5/sig, same layout
#define L_OFF     (W_OFF + NBHW*512)         // [288][32]
#define BM_OFF    (L_OFF + NBHW*32)          // [NBLK] per-block lognum max
#define M_OFF     (BM_OFF + NBLK)            // [4] global lognum max (kC0)
#define LOG_OFF   (M_OFF + 4)                // [288][288][32] lognum
#define DSR_OFF   (LOG_OFF + NBHW*NC*NO)     // [NBLK][32] per-o sumR (kD)
// kD reuses S1/S2 for its partials (kB0 consumed kA's before kD runs).

// ================= kA: m_step 1 partial moments (R uniform = 1/NO) =========
// grid = NBLK, block = 256. Also zeroes the dense grid (consumed by kC/kD).
__global__ __launch_bounds__(256) void kA(const float* __restrict__ votes,
        const float* __restrict__ acts, float* __restrict__ ws) {
    __shared__ float s_acts[CPC];
    __shared__ float4 r1[128], r2[128];
    __shared__ float sR1;
    const int bid = blockIdx.x;
    const int bhw = bid >> 2;
    const int cbase = (bid & 3) * CPC;
    const int t = threadIdx.x;
    {   // fold dense-grid zeroing into the first kernel
        const int idx = bid*256 + t;
        if (idx < DENSE_N) ws[DENSE_OFF + idx] = 0.f;
    }
    if (t < CPC) s_acts[t] = acts[bhw*NC + cbase + t] * (1.0f/NO);
    __syncthreads();
    const int child_sub = t >> 7;
    const int rem = t & 127;
    const float4* vb4 = (const float4*)votes + (size_t)bhw*(VPB/4);
    float s1[4] = {0,0,0,0}, s2[4] = {0,0,0,0};
    float sumR = 0.f;
    #pragma unroll 6
    for (int it = 0; it < ITERS; ++it) {
        const int c_loc = it*2 + child_sub;
        float4 v = vb4[(size_t)(cbase + c_loc)*128 + rem];
        float ra = s_acts[c_loc];
        s1[0] += ra*v.x; s2[0] = fmaf(ra*v.x, v.x, s2[0]);
        s1[1] += ra*v.y; s2[1] = fmaf(ra*v.y, v.y, s2[1]);
        s1[2] += ra*v.z; s2[2] = fmaf(ra*v.z, v.z, s2[2]);
        s1[3] += ra*v.w; s2[3] = fmaf(ra*v.w, v.w, s2[3]);
        sumR += ra;
    }
    if (child_sub) {
        r1[rem] = make_float4(s1[0], s1[1], s1[2], s1[3]);
        r2[rem] = make_float4(s2[0], s2[1], s2[2], s2[3]);
        if (rem == 0) sR1 = sumR;
    }
    __syncthreads();
    if (!child_sub) {
        float4 o1 = r1[rem], o2 = r2[rem];
        ((float4*)(ws + S1_OFF))[bid*128 + rem] =
            make_float4(s1[0]+o1.x, s1[1]+o1.y, s1[2]+o1.z, s1[3]+o1.w);
        ((float4*)(ws + S2_OFF))[bid*128 + rem] =
            make_float4(s2[0]+o2.x, s2[1]+o2.y, s2[2]+o2.z, s2[3]+o2.w);
        if (rem == 0) ws[SR_OFF + bid] = sumR + sR1;
    }
}

// ================= kB0: per-bhw finalize (once per bhw, not per chunk) =====
// grid = NBHW, block = 256. Replaces the 4x-redundant re-reduction that the
// lognum kernel used to do per chunk-block (~19 MB of slot re-reads removed).
__global__ __launch_bounds__(256) void kB0(const float* __restrict__ beta_a,
        const float* __restrict__ beta_u, float* __restrict__ ws) {
    const int bhw = blockIdx.x;
    const int t = threadIdx.x;
    float sumR = 0.f;
    #pragma unroll
    for (int s = 0; s < CH; ++s) sumR += ws[SR_OFF + bhw*CH + s];
    #pragma unroll
    for (int half = 0; half < 2; ++half) {
        const int idx = t + half*256;        // = o*16 + a
        float s1 = 0.f, s2 = 0.f;
        #pragma unroll
        for (int s = 0; s < CH; ++s) {
            s1 += ws[S1_OFF + (size_t)(bhw*CH + s)*512 + idx];
            s2 += ws[S2_OFF + (size_t)(bhw*CH + s)*512 + idx];
        }
        const int o = idx >> 4, a = idx & 15;
        float mu  = s1 / (sumR + EPSF);
        float sig = (s2 - mu*(2.f*s1 - mu*sumR)) / (sumR + EPSF) + MINVAR;
        ws[MU_OFF + bhw*512 + a*32 + o] = mu;
        ws[W_OFF  + bhw*512 + a*32 + o] = 0.5f / sig;
        float cost = (beta_u[o] - 0.5f*logf(sig + EPSF)) * sumR;
        float ps   = logf(6.2831853071795864f * sig);
        #pragma unroll
        for (int d = 1; d < 16; d <<= 1) {
            cost += __shfl_xor(cost, d);
            ps   += __shfl_xor(ps, d);
        }
        if (a == 0) {
            float aj = 1.0f/(1.0f + expf(-TEMP0*(beta_a[o] - cost)));
            ws[L_OFF + bhw*32 + o] = logf(aj) - ps;
        }
    }
}

// ================= kB: lognum pass over votes ===============================
// grid = NBLK, block = 256. Loads mu/w/L from ws (computed once by kB0).
__global__ __launch_bounds__(256) void kB(const float* __restrict__ votes,
        float* __restrict__ ws) {
    __shared__ float s_mu[512], s_w[512], s_L[32], smax[4];
    const int bid = blockIdx.x;
    const int bhw = bid >> 2;
    const int cbase = (bid & 3) * CPC;
    const int t = threadIdx.x;
    s_mu[t]     = ws[MU_OFF + bhw*512 + t];
    s_mu[t+256] = ws[MU_OFF + bhw*512 + t + 256];
    s_w[t]      = ws[W_OFF + bhw*512 + t];
    s_w[t+256]  = ws[W_OFF + bhw*512 + t + 256];
    if (t < 32) s_L[t] = ws[L_OFF + bhw*32 + t];
    __syncthreads();
    const int child_sub = t >> 7;
    const int rem = t & 127;
    const int o = rem >> 2;
    const int quad = rem & 3;
    float mur[4], wr[4];
    #pragma unroll
    for (int j = 0; j < 4; ++j) {
        mur[j] = s_mu[(quad*4 + j)*32 + o];
        wr[j]  = s_w [(quad*4 + j)*32 + o];
    }
    const float L = s_L[o];
    const float4* vb4 = (const float4*)votes + (size_t)bhw*(VPB/4);
    float* lp = ws + LOG_OFF + (size_t)bhw*(NC*NO);
    float tmax = -3.0e38f;
    #pragma unroll 6
    for (int it = 0; it < ITERS; ++it) {
        const int c = cbase + it*2 + child_sub;
        float4 v = vb4[(size_t)c*128 + rem];
        float d0 = v.x - mur[0];
        float acc = d0*d0*wr[0];
        float d1 = v.y - mur[1]; acc = fmaf(d1*d1, wr[1], acc);
        float d2 = v.z - mur[2]; acc = fmaf(d2*d2, wr[2], acc);
        float d3 = v.w - mur[3]; acc = fmaf(d3*d3, wr[3], acc);
        acc += __shfl_xor(acc, 1);
        acc += __shfl_xor(acc, 2);          // all quads hold the full a-sum
        float ln = L - acc;
        if (quad == 0) lp[c*32 + o] = ln;
        tmax = fmaxf(tmax, ln);
    }
    #pragma unroll
    for (int d = 1; d < 64; d <<= 1) tmax = fmaxf(tmax, __shfl_xor(tmax, d));
    if ((t & 63) == 0) smax[t >> 6] = tmax;
    __syncthreads();
    if (t == 0)
        ws[BM_OFF + bid] = fmaxf(fmaxf(smax[0], smax[1]), fmaxf(smax[2], smax[3]));
}

// ================= kC0: global lognum max (once, 1 block) ==================
// Replaces the per-block 1152-entry BM scan that kC and kD each repeated.
__global__ __launch_bounds__(256) void kC0(float* __restrict__ ws) {
    __shared__ float smax[4];
    const int t = threadIdx.x;
    float m = -3.0e38f;
    for (int i = t; i < NBLK; i += 256) m = fmaxf(m, ws[BM_OFF + i]);
    #pragma unroll
    for (int d = 1; d < 64; d <<= 1) m = fmaxf(m, __shfl_xor(m, d));
    if ((t & 63) == 0) smax[t >> 6] = m;
    __syncthreads();
    if (t == 0)
        ws[M_OFF] = fmaxf(fmaxf(smax[0], smax[1]), fmaxf(smax[2], smax[3]));
}

// ================= kC: exp + sum_o ap, scatter to dense ====================
// grid = NBLK, block = 256; t -> (c_loc = t>>5, o = t&31)
__global__ __launch_bounds__(256) void kC(float* __restrict__ ws) {
    const int bid = blockIdx.x;
    const int bhw = bid >> 2;
    const int cbase = (bid & 3) * CPC;
    const int t = threadIdx.x;
    const float M = ws[M_OFF];
    const int b = bhw / (NH*NW);
    const int rem = bhw % (NH*NW);
    const int y = rem / NW, x = rem % NW;
    const float* lp = ws + LOG_OFF + (size_t)bhw*(NC*NO);
    float* dense = ws + DENSE_OFF;
    const int o = t & 31;
    for (int it = 0; it < CPC/8; ++it) {
        const int c = cbase + it*8 + (t >> 5);
        float s = expf(lp[c*32 + o] - M);
        #pragma unroll
        for (int d = 1; d < 32; d <<= 1) s += __shfl_xor(s, d);
        if (o == 0) {
            const int i = c & 31, kk = c >> 5;
            const int ky = kk / 3, kx = kk % 3;
            atomicAdd(&dense[((b*HR + y+ky)*WR + (x+kx))*NI + i], s);
        }
    }
}

// ================= kD: final m_step partial moments ========================
// grid = NBLK, block = 256. Reads global max from ws (no BM rescan).
__global__ __launch_bounds__(256) void kD(const float* __restrict__ votes,
        const float* __restrict__ acts, float* __restrict__ ws) {
    __shared__ float s_rd[CPC];
    __shared__ float s_ra[CPC*NO];
    __shared__ float4 r1[128], r2[128];
    __shared__ float sSR[64];
    const int bid = blockIdx.x;
    const int bhw = bid >> 2;
    const int cbase = (bid & 3) * CPC;
    const int t = threadIdx.x;
    const int b = bhw / (NH*NW);
    const int remhw = bhw % (NH*NW);
    const int y = remhw / NW, x = remhw % NW;
    const float M = ws[M_OFF];
    if (t < CPC) {
        const int c = cbase + t;
        const int i = c & 31, kk = c >> 5;
        const int ky = kk / 3, kx = kk % 3;
        float dn = ws[DENSE_OFF + ((b*HR + y+ky)*WR + (x+kx))*NI + i];
        s_rd[t] = acts[bhw*NC + c] / (dn + EPSF);
    }
    __syncthreads();
    const float* lp = ws + LOG_OFF + (size_t)bhw*(NC*NO) + (size_t)cbase*32;
    for (int idx = t; idx < CPC*NO; idx += 256)
        s_ra[idx] = s_rd[idx >> 5] * expf(lp[idx] - M);
    __syncthreads();
    const int child_sub = t >> 7;
    const int rem = t & 127;
    const int o = rem >> 2;
    const int quad = rem & 3;
    const float4* vb4 = (const float4*)votes + (size_t)bhw*(VPB/4);
    float s1[4] = {0,0,0,0}, s2[4] = {0,0,0,0};
    float sumR = 0.f;
    #pragma unroll 6
    for (int it = 0; it < ITERS; ++it) {
        const int c_loc = it*2 + child_sub;
        float4 v = vb4[(size_t)(cbase + c_loc)*128 + rem];
        float ra = s_ra[c_loc*32 + o];          // 4-lane broadcast
        s1[0] += ra*v.x; s2[0] = fmaf(ra*v.x, v.x, s2[0]);
        s1[1] += ra*v.y; s2[1] = fmaf(ra*v.y, v.y, s2[1]);
        s1[2] += ra*v.z; s2[2] = fmaf(ra*v.z, v.z, s2[2]);
        s1[3] += ra*v.w; s2[3] = fmaf(ra*v.w, v.w, s2[3]);
        sumR += ra;
    }
    // per-(child_sub, o) partial: quads are identical, take quad 0's only
    if (quad == 0) sSR[child_sub*32 + o] = sumR;
    if (child_sub) {
        r1[rem] = make_float4(s1[0], s1[1], s1[2], s1[3]);
        r2[rem] = make_float4(s2[0], s2[1], s2[2], s2[3]);
    }
    __syncthreads();
    if (!child_sub) {
        float4 o1 = r1[rem], o2 = r2[rem];
        ((float4*)(ws + S1_OFF))[bid*128 + rem] =
            make_float4(s1[0]+o1.x, s1[1]+o1.y, s1[2]+o1.z, s1[3]+o1.w);
        ((float4*)(ws + S2_OFF))[bid*128 + rem] =
            make_float4(s2[0]+o2.x, s2[1]+o2.y, s2[2]+o2.z, s2[3]+o2.w);
    }
    if (t < 32) ws[DSR_OFF + bid*32 + t] = sSR[t] + sSR[32 + t];
}

// ================= kD2: reduce chunk slots, write outputs ==================
// grid = NBHW*2, block = 256, t = (o_loc<<4)|a
__global__ __launch_bounds__(256) void kD2(const float* __restrict__ beta_a,
        const float* __restrict__ beta_u, const float* __restrict__ ws,
        float* __restrict__ out) {
    const int bid = blockIdx.x;
    const int bhw = bid >> 1;
    const int obase = (bid & 1) * 16;
    const int t = threadIdx.x;
    const int a = t & 15;
    const int o = obase + (t >> 4);
    float s1 = 0.f, s2 = 0.f, sumR = 0.f;
    #pragma unroll
    for (int ch = 0; ch < CH; ++ch) {
        s1   += ws[S1_OFF + (size_t)(bhw*CH + ch)*512 + obase*16 + t];
        s2   += ws[S2_OFF + (size_t)(bhw*CH + ch)*512 + obase*16 + t];
        sumR += ws[DSR_OFF + (bhw*CH + ch)*32 + o];
    }
    float mu  = s1 / (sumR + EPSF);
    float sig = (s2 - mu*(2.f*s1 - mu*sumR)) / (sumR + EPSF) + MINVAR;
    out[bhw*512 + obase*16 + t] = mu;            // poses (b,h,w,o,a,a)
    float cost = (beta_u[o] - 0.5f*logf(sig + EPSF)) * sumR;
    #pragma unroll
    for (int d = 1; d < 16; d <<= 1) cost += __shfl_xor(cost, d);
    if (a == 0) {
        float aj = 1.0f/(1.0f + expf(-TEMPF*(beta_a[o] - cost)));
        out[NBHW*512 + bhw*32 + o] = aj;         // acts (b,h,w,o)
    }
}

extern "C" void kernel_launch(void* const* d_in, const int* in_sizes, int n_in,
                              void* d_out, int out_size, void* d_ws, size_t ws_size,
                              hipStream_t stream) {
    const float* votes  = (const float*)d_in[0];
    const float* acts   = (const float*)d_in[1];
    const float* beta_a = (const float*)d_in[2];
    const float* beta_u = (const float*)d_in[3];
    float* ws  = (float*)d_ws;
    float* out = (float*)d_out;

    kA <<<NBLK,   256, 0, stream>>>(votes, acts, ws);
    kB0<<<NBHW,   256, 0, stream>>>(beta_a, beta_u, ws);
    kB <<<NBLK,   256, 0, stream>>>(votes, ws);
    kC0<<<1,      256, 0, stream>>>(ws);
    kC <<<NBLK,   256, 0, stream>>>(ws);
    kD <<<NBLK,   256, 0, stream>>>(votes, acts, ws);
    kD2<<<NBHW*2, 256, 0, stream>>>(beta_a, beta_u, ws, out);
}